// Round 6
// baseline (280.334 us; speedup 1.0000x reference)
//
#include <hip/hip_runtime.h>
#include <math.h>

constexpr int S_LEN = 4096;
constexpr int W     = 32;            // steps per window
constexpr int NP    = W / 2;         // 16 step-pairs per window
constexpr int NW    = S_LEN / W;     // 128 windows
constexpr int CPB   = 32;            // chains per block
constexpr int NT    = 256;           // 4 waves: wave0 consumer, waves 1-3 producers

// lane 2k <-> 2k+1 swap via DPP quad_perm [1,0,3,2]
__device__ __forceinline__ float pair_swap(float v) {
    int j = __builtin_amdgcn_mov_dpp(__builtin_bit_cast(int, v), 0xB1, 0xF, 0xF, true);
    return __builtin_bit_cast(float, j);
}

// Quaternion reformulation + pair-fused deferred-norm consumer (numerics verified R5).
//   u_{t+1} = N(u_t + b_t),  b_t = L e_t R^{-(t+1)};  measurement invariant under R^S.
//   C=cos((t+1)b/2), S=sin((t+1)b/2), e1=cC,e2=cS,e3=sC,e4=sS:
//   b = ( ca e1 - sa e4, -(ca e2 + sa e3), ca e3 - sa e2, sa e1 + ca e4 )
// LDS layout (R6 fix: every bulk access is 64 lanes x consecutive 16B -> conflict-free):
//   bbuf4[sel][pair][2c+p] = (b0[2p],b0[2p+1],b1[2p],b1[2p+1])
//     producer: lane L writes slot [pair][L]   (ds_write_b128, consecutive)
//     consumer: lane L reads  slot [pair][L]   (ds_read_b128,  consecutive)
//   c01buf[sel][pair][c] = <b0,b1>  (in-lane dot; p==0 half-wave writes 128B consecutive)
__global__ __launch_bounds__(NT)
void qrnn_kernel(const float* __restrict__ x,
                 const float* __restrict__ alpha_p,
                 const float* __restrict__ beta_p,
                 float* __restrict__ out)
{
    __shared__ float4 bbuf4[2 * NP * 64];     // 32 KB
    __shared__ float  c01buf[2 * NP * CPB];   //  4 KB
    __shared__ float2 wtab[NW];               //  1 KB  cs(w*32*hb)
    __shared__ float2 stab[W];                // 256 B  cs((s+1)*hb)

    const int tid = threadIdx.x;

    // ---- two-level (C,S) tables, f64 angle reduction (verified R5) ----
    {
        const double hb     = 0.5 * (double)beta_p[0];
        const double twopi  = 6.283185307179586476925287;
        const double inv2pi = 0.15915494309189533576888;
        for (int t = tid; t < NW + W; t += NT) {
            double ang = (t < NW) ? (double)(t * W) * hb : (double)(t - NW + 1) * hb;
            ang -= floor(ang * inv2pi) * twopi;
            float sv, cv;
            __sincosf((float)ang, &sv, &cv);
            if (t < NW) wtab[t] = make_float2(cv, sv);
            else        stab[t - NW] = make_float2(cv, sv);
        }
    }
    __syncthreads();

    const int wave = tid >> 6;
    const int lane = tid & 63;

    if (wave != 0) {
        // ================= PRODUCERS (waves 1..3) =================
        float sa, ca;
        __sincosf(0.5f * alpha_p[0], &sa, &ca);

        const int c = lane >> 1;             // chain within block
        const int p = lane & 1;              // which slot half this lane writes
        // float4-group assignment, round-robin: wave1:{0,3,6} wave2:{1,4,7} wave3:{2,5}
        const int wv = wave - 1;             // 0..2
        const int ng = (wv < 2) ? 3 : 2;
        int glist[3] = {wv, wv + 3, wv + 6};

        const float4* __restrict__ xrow =
            reinterpret_cast<const float4*>(x) +
            (size_t)(blockIdx.x * CPB + c) * (S_LEN / 4);

        float4 xa[3];                         // prefetched groups of next window

        auto fill = [&](int w, const float4* xv) {
            const int sel  = w & 1;
            const float2 wt = wtab[w];
#pragma unroll
            for (int gi = 0; gi < 3; ++gi) {
                if (gi >= ng) break;
                const int g = glist[gi];
                float xs[4] = {xv[gi].x, xv[gi].y, xv[gi].z, xv[gi].w};
#pragma unroll
                for (int q = 0; q < 2; ++q) {
                    const int j = 2 * g + q;          // pair index 0..15
                    float b0[4], b1[4];
#pragma unroll
                    for (int ii = 0; ii < 2; ++ii) {
                        const int s = 4 * g + 2 * q + ii;   // step-in-window
                        float2 st = stab[s];
                        float C = __builtin_fmaf(wt.x, st.x, -(wt.y * st.y));
                        float S = __builtin_fmaf(wt.y, st.x,  (wt.x * st.y));
                        float xt  = xs[2 * q + ii];
                        float t1  = __builtin_fmaf(xt, xt, 1.0f);
                        float r   = __frsqrt_rn(t1);                 // cos(phi)
                        float wvv = __builtin_fmaf(0.5f, r, 0.5f);   // c^2
                        float v   = __frsqrt_rn(wvv);
                        float cc  = wvv * v;                         // c
                        float xr  = xt * r;                          // sin(phi)
                        float ssv = xr * (0.5f * v);                 // s
                        float e1 = cc * C,  e2 = cc * S;
                        float e3 = ssv * C, e4 = ssv * S;
                        float* b = ii ? b1 : b0;
                        b[0] =  __builtin_fmaf(ca, e1, -(sa * e4));
                        b[1] = -__builtin_fmaf(ca, e2,  (sa * e3));
                        b[2] =  __builtin_fmaf(ca, e3, -(sa * e2));
                        b[3] =  __builtin_fmaf(sa, e1,  (ca * e4));
                    }
                    float c01 = b0[0] * b1[0];
                    c01 = __builtin_fmaf(b0[1], b1[1], c01);
                    c01 = __builtin_fmaf(b0[2], b1[2], c01);
                    c01 = __builtin_fmaf(b0[3], b1[3], c01);
                    // parity-selected half -> slot [sel][j][lane]: consecutive 16B/lane
                    float s0 = p ? b0[2] : b0[0];
                    float s1 = p ? b0[3] : b0[1];
                    float s2 = p ? b1[2] : b1[0];
                    float s3 = p ? b1[3] : b1[1];
                    bbuf4[(sel * NP + j) * 64 + lane] = make_float4(s0, s1, s2, s3);
                    if (p == 0) c01buf[(sel * NP + j) * CPB + c] = c01;
                }
            }
        };

        // window 0: fresh loads, fill, prefetch window 1
        {
            float4 x0[3];
#pragma unroll
            for (int gi = 0; gi < 3; ++gi) if (gi < ng) x0[gi] = xrow[glist[gi]];
            fill(0, x0);
#pragma unroll
            for (int gi = 0; gi < 3; ++gi) if (gi < ng) xa[gi] = xrow[8 + glist[gi]];
        }
        __syncthreads();                      // window 0 ready

        for (int w = 0; w < NW; ++w) {
            if (w + 1 < NW) {
                float4 xv[3];
#pragma unroll
                for (int gi = 0; gi < 3; ++gi) xv[gi] = xa[gi];
                if (w + 2 < NW) {
#pragma unroll
                    for (int gi = 0; gi < 3; ++gi)
                        if (gi < ng) xa[gi] = xrow[(w + 2) * 8 + glist[gi]];
                }
                fill(w + 1, xv);
            }
            __syncthreads();
        }
    } else {
        // ================= CONSUMER (wave 0) =================
        const int p   = lane & 1;
        const int chn = lane >> 1;

        float gx = 0.f, gy = 0.f, rn = 1.f, rn2 = 2.f;

        __syncthreads();                      // wait window 0

        for (int w = 0; w < NW; ++w) {
            const int sel = w & 1;
            const float4* __restrict__ bb = &bbuf4[sel * NP * 64 + lane];
            const float*  __restrict__ cp = &c01buf[sel * NP * CPB + chn];

            auto pairstep = [&](int j) {
                float4 v   = bb[j * 64];
                float c01v = cp[j * CPB];
                float d0p = __builtin_fmaf(gy, v.y, gx * v.x);
                float d1p = __builtin_fmaf(gy, v.w, gx * v.z);
                float d0  = d0p + pair_swap(d0p);
                float d1  = d1p + pair_swap(d1p);
                float m0   = __builtin_fmaf(rn2, d0, 2.0f);
                float rn0  = __frsqrt_rn(m0);
                float rn02 = rn0 + rn0;
                float e1   = __builtin_fmaf(rn, d1, c01v);
                float m1   = __builtin_fmaf(rn02, e1, 2.0f);
                float ngx  = __builtin_fmaf(rn, gx, v.x);
                float ngy  = __builtin_fmaf(rn, gy, v.y);
                gx = __builtin_fmaf(rn0, ngx, v.z);
                gy = __builtin_fmaf(rn0, ngy, v.w);
                rn = __frsqrt_rn(m1);
                rn2 = rn + rn;
            };

            if (w == 0) {
                // pair 0 peeled exactly: u2 = N(b0 + b1), |b0|=|b1|=1
                float4 v   = bb[0];
                float c01v = cp[0];
                gx = v.x + v.z;
                gy = v.y + v.w;
                rn = __frsqrt_rn(__builtin_fmaf(c01v, 2.0f, 2.0f));
                rn2 = rn + rn;
#pragma unroll
                for (int j = 1; j < NP; ++j) pairstep(j);
            } else {
#pragma unroll
                for (int j = 0; j < NP; ++j) pairstep(j);
            }
            __syncthreads();
        }

        float ss = __builtin_fmaf(gy, gy, gx * gx);
        float so = pair_swap(ss);
        if (p == 0) out[blockIdx.x * CPB + chn] = (ss - so) / (ss + so);
    }
}

extern "C" void kernel_launch(void* const* d_in, const int* in_sizes, int n_in,
                              void* d_out, int out_size, void* d_ws, size_t ws_size,
                              hipStream_t stream) {
    const float* x       = (const float*)d_in[0];
    const float* alpha_p = (const float*)d_in[1];
    const float* beta_p  = (const float*)d_in[2];
    float* out = (float*)d_out;
    int grid = out_size / CPB;               // 8192/32 = 256 blocks
    qrnn_kernel<<<grid, NT, 0, stream>>>(x, alpha_p, beta_p, out);
}